// Round 10
// baseline (250.275 us; speedup 1.0000x reference)
//
#include <hip/hip_runtime.h>
#include <hip/hip_bf16.h>

typedef __attribute__((ext_vector_type(8))) short short8v;
typedef __attribute__((ext_vector_type(4))) float floatx4;

__device__ __forceinline__ unsigned short f2bf(float f) {
    unsigned b = __float_as_uint(f);
    b = (b + 0x7fffu + ((b >> 16) & 1u)) >> 16;
    return (unsigned short)b;
}
__device__ __forceinline__ float b2f(unsigned short u) {
    return __uint_as_float((unsigned)u << 16);
}

// ------ fused front: x->bf16, W_gat/W_lin -> transposed bf16 [col][k],
//        and dst histogram over the E real edges --------------------------
__global__ void k_prep(const float* __restrict__ x, unsigned short* __restrict__ xb, int n0,
                       const float* __restrict__ Wg, unsigned short* __restrict__ wbT,
                       const float* __restrict__ Wl, unsigned short* __restrict__ wlbT,
                       const int* __restrict__ ei, int* __restrict__ cnt, int E) {
    const int TG = 256 * 256 / 4;   // W_gat f4 chunks
    const int TL = 256 * 64 / 4;    // W_lin f4 chunks
    int total = n0 + TG + TL + E;
    int i = blockIdx.x * blockDim.x + threadIdx.x;
    int stride = gridDim.x * blockDim.x;
    for (; i < total; i += stride) {
        if (i < n0) {
            float4 v = reinterpret_cast<const float4*>(x)[i];
            ushort4 o;
            o.x = f2bf(v.x); o.y = f2bf(v.y); o.z = f2bf(v.z); o.w = f2bf(v.w);
            reinterpret_cast<ushort4*>(xb)[i] = o;
        } else if (i < n0 + TG) {
            int j = i - n0;
            int k = j >> 6, c4 = (j & 63) * 4;
            float4 v = *reinterpret_cast<const float4*>(Wg + k * 256 + c4);
            wbT[(size_t)(c4 + 0) * 256 + k] = f2bf(v.x);
            wbT[(size_t)(c4 + 1) * 256 + k] = f2bf(v.y);
            wbT[(size_t)(c4 + 2) * 256 + k] = f2bf(v.z);
            wbT[(size_t)(c4 + 3) * 256 + k] = f2bf(v.w);
        } else if (i < n0 + TG + TL) {
            int j = i - n0 - TG;
            int k = j >> 4, c4 = (j & 15) * 4;
            float4 v = *reinterpret_cast<const float4*>(Wl + k * 64 + c4);
            wlbT[(size_t)(c4 + 0) * 256 + k] = f2bf(v.x);
            wlbT[(size_t)(c4 + 1) * 256 + k] = f2bf(v.y);
            wlbT[(size_t)(c4 + 2) * 256 + k] = f2bf(v.z);
            wlbT[(size_t)(c4 + 3) * 256 + k] = f2bf(v.w);
        } else {
            int e = i - n0 - TG - TL;
            atomicAdd(&cnt[ei[E + e]], 1);
        }
    }
}

// ---------------- hierarchical exclusive scan (+1 self-loop per node) -------
#define SCAN_NB 256
__launch_bounds__(256)
__global__ void k_scan_a(const int* __restrict__ cnt, int* __restrict__ bsum, int N) {
    __shared__ int sh[256];
    int b = blockIdx.x, t = threadIdx.x;
    int chunk = (N + SCAN_NB - 1) / SCAN_NB;
    int idx = b * chunk + t;
    sh[t] = (t < chunk && idx < N) ? (cnt[idx] + 1) : 0;   // +1: self-loop
    __syncthreads();
    for (int off = 128; off > 0; off >>= 1) {
        if (t < off) sh[t] += sh[t + off];
        __syncthreads();
    }
    if (t == 0) bsum[b] = sh[0];
}
// fused: scan of block sums (redundant in-LDS) + per-chunk exclusive scan;
// pre-places the self-loop at row start and starts cursor past it.
__launch_bounds__(256)
__global__ void k_scan_bc(const int* __restrict__ cnt, const int* __restrict__ bsum,
                          int* __restrict__ row_start, int* __restrict__ cursor,
                          unsigned short* __restrict__ ssrc, int N) {
    __shared__ int shb[256];
    __shared__ int sh[256];
    int b = blockIdx.x, t = threadIdx.x;
    shb[t] = bsum[t];
    __syncthreads();
    for (int off = 1; off < 256; off <<= 1) {
        int v = (t >= off) ? shb[t - off] : 0;
        __syncthreads();
        shb[t] += v;
        __syncthreads();
    }
    int boff = (b == 0) ? 0 : shb[b - 1];

    int chunk = (N + SCAN_NB - 1) / SCAN_NB;
    int idx = b * chunk + t;
    int v = (t < chunk && idx < N) ? (cnt[idx] + 1) : 0;
    sh[t] = v;
    __syncthreads();
    for (int off = 1; off < 256; off <<= 1) {
        int u = (t >= off) ? sh[t - off] : 0;
        __syncthreads();
        sh[t] += u;
        __syncthreads();
    }
    if (t < chunk && idx < N) {
        int ex = boff + sh[t] - v;       // row start
        row_start[idx] = ex;
        cursor[idx] = ex + 1;            // slot 0 = self-loop
        ssrc[ex] = (unsigned short)idx;
    }
}

// ------ fused: GEMM1 (+attn epilogue, LDS-free)  ||  scatter (4 edges/thr) --
__launch_bounds__(256)
__global__ void k_gs(const unsigned short* __restrict__ A,
                     const unsigned short* __restrict__ BT,   // [col][k] bf16
                     const float* __restrict__ att_src, const float* __restrict__ att_dst,
                     unsigned short* __restrict__ hb,
                     float* __restrict__ a_src, float* __restrict__ a_dst,
                     int M, int RB, int GB1,
                     const int* __restrict__ ei, int* __restrict__ cursor,
                     unsigned short* __restrict__ ssrc, int E) {
    const int b = blockIdx.x;
    const int tid = threadIdx.x;
    if (b >= GB1) {
        // ---- scatter: 4 edges per thread, independent atomic chains ----
        int e0 = ((b - GB1) * 256 + tid) * 4;
        if (e0 >= E) return;
        int4 s4 = *reinterpret_cast<const int4*>(ei + e0);
        int4 d4 = *reinterpret_cast<const int4*>(ei + E + e0);
        int p0 = atomicAdd(&cursor[d4.x], 1);
        int p1 = atomicAdd(&cursor[d4.y], 1);
        int p2 = atomicAdd(&cursor[d4.z], 1);
        int p3 = atomicAdd(&cursor[d4.w], 1);
        ssrc[p0] = (unsigned short)s4.x;
        ssrc[p1] = (unsigned short)s4.y;
        ssrc[p2] = (unsigned short)s4.z;
        ssrc[p3] = (unsigned short)s4.w;
        return;
    }
    // ---- gemm1: B fragments direct from L1/L2-resident BT ----
    const int nt = b / RB;
    const int tM = (b - nt * RB) * 64;
    const int w  = tid >> 6;
    const int l  = tid & 63;
    const int lg = l >> 4;
    const int lr = l & 15;

    int rowA = tM + w * 16 + lr;
    if (rowA > M - 1) rowA = M - 1;
    const unsigned short* Arow = A + (size_t)rowA * 256 + lg * 8;
    short8v av[8];
#pragma unroll
    for (int kt = 0; kt < 8; ++kt)
        av[kt] = *reinterpret_cast<const short8v*>(Arow + kt * 32);

    const unsigned short* Bt = BT + (size_t)(nt * 64) * 256 + lg * 8;
    floatx4 acc[4] = {};
#pragma unroll
    for (int kt = 0; kt < 8; ++kt) {
#pragma unroll
        for (int n = 0; n < 4; ++n) {
            short8v bv = *reinterpret_cast<const short8v*>(Bt + (size_t)(n * 16 + lr) * 256 + kt * 32);
            acc[n] = __builtin_amdgcn_mfma_f32_16x16x32_bf16(av[kt], bv, acc[n], 0, 0, 0);
        }
    }

    float ps[2][4] = {}, pd[2][4] = {};
#pragma unroll
    for (int n = 0; n < 4; ++n) {
        int hd2 = n >> 1;
        float asv = att_src[(nt * 2 + hd2) * 32 + (n & 1) * 16 + lr];
        float adv = att_dst[(nt * 2 + hd2) * 32 + (n & 1) * 16 + lr];
        int col = nt * 64 + n * 16 + lr;
#pragma unroll
        for (int r = 0; r < 4; ++r) {
            int row = tM + w * 16 + lg * 4 + r;  // C/D: row=(lane>>4)*4+reg
            float v = acc[n][r];
            if (row < M) hb[(size_t)row * 256 + col] = f2bf(v);
            ps[hd2][r] += v * asv;
            pd[hd2][r] += v * adv;
        }
    }
#pragma unroll
    for (int off = 1; off < 16; off <<= 1) {
#pragma unroll
        for (int hd2 = 0; hd2 < 2; ++hd2)
#pragma unroll
            for (int r = 0; r < 4; ++r) {
                ps[hd2][r] += __shfl_xor(ps[hd2][r], off, 64);
                pd[hd2][r] += __shfl_xor(pd[hd2][r], off, 64);
            }
    }
    if (lr == 0) {
#pragma unroll
        for (int hd2 = 0; hd2 < 2; ++hd2)
#pragma unroll
            for (int r = 0; r < 4; ++r) {
                int row = tM + w * 16 + lg * 4 + r;
                if (row < M) {
                    a_src[(size_t)row * 8 + nt * 2 + hd2] = ps[hd2][r];
                    a_dst[(size_t)row * 8 + nt * 2 + hd2] = pd[hd2][r];
                }
            }
    }
}

// ------ GEMM2 (LDS-free): out[M,64] = g @ W_lin + b_lin ---------------------
__launch_bounds__(256)
__global__ void k_gemm2(const unsigned short* __restrict__ A,
                        const unsigned short* __restrict__ BT,  // [col][k]
                        float* __restrict__ C,
                        const float* __restrict__ bias, int M) {
    const int tid = threadIdx.x;
    const int tM = blockIdx.x * 64;
    const int w  = tid >> 6;
    const int l  = tid & 63;
    const int lg = l >> 4;
    const int lr = l & 15;

    int rowA = tM + w * 16 + lr;
    if (rowA > M - 1) rowA = M - 1;
    const unsigned short* Arow = A + (size_t)rowA * 256 + lg * 8;
    const unsigned short* Bt = BT + lg * 8;

    floatx4 acc[4] = {};
#pragma unroll
    for (int kt = 0; kt < 8; ++kt) {
        short8v av = *reinterpret_cast<const short8v*>(Arow + kt * 32);
#pragma unroll
        for (int n = 0; n < 4; ++n) {
            short8v bv = *reinterpret_cast<const short8v*>(Bt + (size_t)(n * 16 + lr) * 256 + kt * 32);
            acc[n] = __builtin_amdgcn_mfma_f32_16x16x32_bf16(av, bv, acc[n], 0, 0, 0);
        }
    }
#pragma unroll
    for (int n = 0; n < 4; ++n) {
        int col = n * 16 + lr;
        float badd = bias[col];
#pragma unroll
        for (int r = 0; r < 4; ++r) {
            int row = tM + w * 16 + lg * 4 + r;
            if (row < M) C[(size_t)row * 64 + col] = acc[n][r] + badd;
        }
    }
}

// ------ fused aggregate: softmax-weighted sum + bias + relu -> bf16 ---------
__launch_bounds__(256)
__global__ void k_agg(const int* __restrict__ row_start, const int* __restrict__ row_end,
                      const unsigned short* __restrict__ sorted_src,
                      const float* __restrict__ a_src, const float* __restrict__ a_dst,
                      const unsigned short* __restrict__ hb,
                      const float* __restrict__ bias_gat,
                      unsigned short* __restrict__ gb, int N) {
    int n = blockIdx.x * 4 + (threadIdx.x >> 6);
    if (n >= N) return;
    int lane = threadIdx.x & 63;
    int hd = lane >> 3;
    int start = row_start[n], end = row_end[n];
    float ad = a_dst[(size_t)n * 8 + hd];
    float ax = 0.f, ay = 0.f, az = 0.f, aw = 0.f, den = 0.f;
    float bx = 0.f, by = 0.f, bz = 0.f, bw = 0.f, den2 = 0.f;
    for (int j0 = start; j0 < end; j0 += 64) {
        int idx = j0 + lane;
        int sv = (idx < end) ? (int)sorted_src[idx] : 0;
        int cnt = end - j0; if (cnt > 64) cnt = 64;
        int jj = 0;
        for (; jj + 3 < cnt; jj += 4) {
            int s0 = __shfl(sv, jj);
            int s1 = __shfl(sv, jj + 1);
            int s2 = __shfl(sv, jj + 2);
            int s3 = __shfl(sv, jj + 3);
            float v0 = a_src[(size_t)s0 * 8 + hd] + ad;
            float v1 = a_src[(size_t)s1 * 8 + hd] + ad;
            float v2 = a_src[(size_t)s2 * 8 + hd] + ad;
            float v3 = a_src[(size_t)s3 * 8 + hd] + ad;
            ushort4 h0 = *reinterpret_cast<const ushort4*>(hb + (size_t)s0 * 256 + lane * 4);
            ushort4 h1 = *reinterpret_cast<const ushort4*>(hb + (size_t)s1 * 256 + lane * 4);
            ushort4 h2 = *reinterpret_cast<const ushort4*>(hb + (size_t)s2 * 256 + lane * 4);
            ushort4 h3 = *reinterpret_cast<const ushort4*>(hb + (size_t)s3 * 256 + lane * 4);
            v0 = v0 > 0.f ? v0 : 0.2f * v0;
            v1 = v1 > 0.f ? v1 : 0.2f * v1;
            v2 = v2 > 0.f ? v2 : 0.2f * v2;
            v3 = v3 > 0.f ? v3 : 0.2f * v3;
            float e0 = __expf(v0), e1 = __expf(v1), e2 = __expf(v2), e3 = __expf(v3);
            den  += e0 + e2; den2 += e1 + e3;
            ax += e0 * b2f(h0.x); ay += e0 * b2f(h0.y);
            az += e0 * b2f(h0.z); aw += e0 * b2f(h0.w);
            bx += e1 * b2f(h1.x); by += e1 * b2f(h1.y);
            bz += e1 * b2f(h1.z); bw += e1 * b2f(h1.w);
            ax += e2 * b2f(h2.x); ay += e2 * b2f(h2.y);
            az += e2 * b2f(h2.z); aw += e2 * b2f(h2.w);
            bx += e3 * b2f(h3.x); by += e3 * b2f(h3.y);
            bz += e3 * b2f(h3.z); bw += e3 * b2f(h3.w);
        }
        for (; jj < cnt; ++jj) {
            int s0 = __shfl(sv, jj);
            float v0 = a_src[(size_t)s0 * 8 + hd] + ad;
            v0 = v0 > 0.f ? v0 : 0.2f * v0;
            float e0 = __expf(v0);
            ushort4 h0 = *reinterpret_cast<const ushort4*>(hb + (size_t)s0 * 256 + lane * 4);
            den += e0;
            ax += e0 * b2f(h0.x); ay += e0 * b2f(h0.y);
            az += e0 * b2f(h0.z); aw += e0 * b2f(h0.w);
        }
    }
    float inv = 1.0f / (den + den2 + 1e-16f);
    float4 b4 = *reinterpret_cast<const float4*>(bias_gat + lane * 4);
    ushort4 o;
    o.x = f2bf(fmaxf((ax + bx) * inv + b4.x, 0.f));
    o.y = f2bf(fmaxf((ay + by) * inv + b4.y, 0.f));
    o.z = f2bf(fmaxf((az + bz) * inv + b4.z, 0.f));
    o.w = f2bf(fmaxf((aw + bw) * inv + b4.w, 0.f));
    reinterpret_cast<ushort4*>(gb)[(size_t)n * 64 + lane] = o;
}

extern "C" void kernel_launch(void* const* d_in, const int* in_sizes, int n_in,
                              void* d_out, int out_size, void* d_ws, size_t ws_size,
                              hipStream_t stream) {
    const float* x        = (const float*)d_in[0];
    const int*   ei       = (const int*)d_in[1];
    const float* W_gat    = (const float*)d_in[2];
    const float* att_src  = (const float*)d_in[3];
    const float* att_dst  = (const float*)d_in[4];
    const float* bias_gat = (const float*)d_in[5];
    const float* W_lin    = (const float*)d_in[6];
    const float* b_lin    = (const float*)d_in[7];
    float* out = (float*)d_out;

    const int N  = in_sizes[0] / 256;   // 50000
    const int E  = in_sizes[1] / 2;     // 800000
    const int EE = E + N;

    char* ws = (char*)d_ws;
    size_t off = 0;
    auto alloc = [&](size_t bytes) -> void* {
        void* p = ws + off;
        off = (off + bytes + 255) & ~(size_t)255;
        return p;
    };
    unsigned short* hb       = (unsigned short*)alloc((size_t)N * 256 * 2);
    float*          a_srcv   = (float*)alloc((size_t)N * 8 * 4);
    float*          a_dstv   = (float*)alloc((size_t)N * 8 * 4);
    int*            cnt      = (int*)alloc((size_t)N * 4);
    int*            rowst    = (int*)alloc((size_t)N * 4);
    int*            cursor   = (int*)alloc((size_t)N * 4);
    int*            bsum     = (int*)alloc(SCAN_NB * 4);
    unsigned short* ssrc     = (unsigned short*)alloc((size_t)EE * 2);
    unsigned short* xb       = (unsigned short*)alloc((size_t)N * 256 * 2);  // reused as gb
    unsigned short* wbT      = (unsigned short*)alloc(256 * 256 * 2);
    unsigned short* wlbT     = (unsigned short*)alloc(64 * 256 * 2);

    hipMemsetAsync(cnt, 0, (size_t)N * 4, stream);

    // conversions + W transposes + histogram
    k_prep<<<2048, 256, 0, stream>>>(x, xb, N * 256 / 4,
                                     W_gat, wbT, W_lin, wlbT, ei, cnt, E);

    // counting-sort scan (+ self-loop pre-placement)
    k_scan_a<<<SCAN_NB, 256, 0, stream>>>(cnt, bsum, N);
    k_scan_bc<<<SCAN_NB, 256, 0, stream>>>(cnt, bsum, rowst, cursor, ssrc, N);

    // fused GEMM1(+attn epilogue, LDS-free) || scatter (4 edges/thread)
    const int RB  = (N + 63) / 64;
    const int GB1 = RB * 4;
    const int SB  = (E / 4 + 255) / 256;
    k_gs<<<GB1 + SB, 256, 0, stream>>>(xb, wbT, att_src, att_dst, hb, a_srcv, a_dstv,
                                       N, RB, GB1, ei, cursor, ssrc, E);

    // fused segment softmax + aggregate + bias + relu -> bf16 (into xb as gb)
    k_agg<<<(N + 3) / 4, 256, 0, stream>>>(rowst, cursor, ssrc, a_srcv, a_dstv, hb,
                                           bias_gat, xb, N);

    // GEMM2: out = g @ W_lin + b_lin
    k_gemm2<<<(N + 63) / 64, 256, 0, stream>>>(xb, wlbT, out, b_lin, N);
}

// Round 11
// 195.156 us; speedup vs baseline: 1.2824x; 1.2824x over previous
//
#include <hip/hip_runtime.h>
#include <hip/hip_bf16.h>

typedef __attribute__((ext_vector_type(8))) short short8v;
typedef __attribute__((ext_vector_type(4))) float floatx4;

__device__ __forceinline__ unsigned short f2bf(float f) {
    unsigned b = __float_as_uint(f);
    b = (b + 0x7fffu + ((b >> 16) & 1u)) >> 16;
    return (unsigned short)b;
}
__device__ __forceinline__ float b2f(unsigned short u) {
    return __uint_as_float((unsigned)u << 16);
}

// ------ fused front: x->bf16, W_gat/W_lin -> transposed bf16 [col][k],
//        and dst histogram over the E real edges --------------------------
__global__ void k_prep(const float* __restrict__ x, unsigned short* __restrict__ xb, int n0,
                       const float* __restrict__ Wg, unsigned short* __restrict__ wbT,
                       const float* __restrict__ Wl, unsigned short* __restrict__ wlbT,
                       const int* __restrict__ ei, int* __restrict__ cnt, int E) {
    const int TG = 256 * 256 / 4;
    const int TL = 256 * 64 / 4;
    int total = n0 + TG + TL + E;
    int i = blockIdx.x * blockDim.x + threadIdx.x;
    int stride = gridDim.x * blockDim.x;
    for (; i < total; i += stride) {
        if (i < n0) {
            float4 v = reinterpret_cast<const float4*>(x)[i];
            ushort4 o;
            o.x = f2bf(v.x); o.y = f2bf(v.y); o.z = f2bf(v.z); o.w = f2bf(v.w);
            reinterpret_cast<ushort4*>(xb)[i] = o;
        } else if (i < n0 + TG) {
            int j = i - n0;
            int k = j >> 6, c4 = (j & 63) * 4;
            float4 v = *reinterpret_cast<const float4*>(Wg + k * 256 + c4);
            wbT[(size_t)(c4 + 0) * 256 + k] = f2bf(v.x);
            wbT[(size_t)(c4 + 1) * 256 + k] = f2bf(v.y);
            wbT[(size_t)(c4 + 2) * 256 + k] = f2bf(v.z);
            wbT[(size_t)(c4 + 3) * 256 + k] = f2bf(v.w);
        } else if (i < n0 + TG + TL) {
            int j = i - n0 - TG;
            int k = j >> 4, c4 = (j & 15) * 4;
            float4 v = *reinterpret_cast<const float4*>(Wl + k * 64 + c4);
            wlbT[(size_t)(c4 + 0) * 256 + k] = f2bf(v.x);
            wlbT[(size_t)(c4 + 1) * 256 + k] = f2bf(v.y);
            wlbT[(size_t)(c4 + 2) * 256 + k] = f2bf(v.z);
            wlbT[(size_t)(c4 + 3) * 256 + k] = f2bf(v.w);
        } else {
            int e = i - n0 - TG - TL;
            atomicAdd(&cnt[ei[E + e]], 1);
        }
    }
}

// ---------------- hierarchical exclusive scan (+1 self-loop per node) -------
#define SCAN_NB 256
__launch_bounds__(256)
__global__ void k_scan_a(const int* __restrict__ cnt, int* __restrict__ bsum, int N) {
    __shared__ int sh[256];
    int b = blockIdx.x, t = threadIdx.x;
    int chunk = (N + SCAN_NB - 1) / SCAN_NB;
    int idx = b * chunk + t;
    sh[t] = (t < chunk && idx < N) ? (cnt[idx] + 1) : 0;   // +1: self-loop
    __syncthreads();
    for (int off = 128; off > 0; off >>= 1) {
        if (t < off) sh[t] += sh[t + off];
        __syncthreads();
    }
    if (t == 0) bsum[b] = sh[0];
}
__launch_bounds__(256)
__global__ void k_scan_bc(const int* __restrict__ cnt, const int* __restrict__ bsum,
                          int* __restrict__ row_start, int* __restrict__ cursor,
                          unsigned short* __restrict__ ssrc, int N) {
    __shared__ int shb[256];
    __shared__ int sh[256];
    int b = blockIdx.x, t = threadIdx.x;
    shb[t] = bsum[t];
    __syncthreads();
    for (int off = 1; off < 256; off <<= 1) {
        int v = (t >= off) ? shb[t - off] : 0;
        __syncthreads();
        shb[t] += v;
        __syncthreads();
    }
    int boff = (b == 0) ? 0 : shb[b - 1];

    int chunk = (N + SCAN_NB - 1) / SCAN_NB;
    int idx = b * chunk + t;
    int v = (t < chunk && idx < N) ? (cnt[idx] + 1) : 0;
    sh[t] = v;
    __syncthreads();
    for (int off = 1; off < 256; off <<= 1) {
        int u = (t >= off) ? sh[t - off] : 0;
        __syncthreads();
        sh[t] += u;
        __syncthreads();
    }
    if (t < chunk && idx < N) {
        int ex = boff + sh[t] - v;
        row_start[idx] = ex;
        cursor[idx] = ex + 1;            // slot 0 = self-loop
        ssrc[ex] = (unsigned short)idx;
    }
}

// ------ fused: GEMM1 (LDS-staged, 8 waves, +attn epilogue) || scatter -------
// blocks [0,GB1): gemm1 over 128-row stripes x 4 col-tiles.
// blocks [GB1,..): scatter, 4 edges/thread.
// 512 thr + 33KB LDS -> 4 blocks/CU = 32 waves/CU (100% occupancy).
__launch_bounds__(512)
__global__ void k_gs(const unsigned short* __restrict__ A,
                     const unsigned short* __restrict__ BT,   // [col][k] bf16
                     const float* __restrict__ att_src, const float* __restrict__ att_dst,
                     unsigned short* __restrict__ hb,
                     float* __restrict__ a_src, float* __restrict__ a_dst,
                     int M, int RB, int GB1,
                     const int* __restrict__ ei, int* __restrict__ cursor,
                     unsigned short* __restrict__ ssrc, int E) {
    __shared__ unsigned short BsT[64 * 264];   // [col][k], stride 264 (bank-balanced)
    const int b = blockIdx.x;
    const int tid = threadIdx.x;
    if (b >= GB1) {
        int e0 = ((b - GB1) * 512 + tid) * 4;
        if (e0 >= E) return;
        int4 s4 = *reinterpret_cast<const int4*>(ei + e0);
        int4 d4 = *reinterpret_cast<const int4*>(ei + E + e0);
        int p0 = atomicAdd(&cursor[d4.x], 1);
        int p1 = atomicAdd(&cursor[d4.y], 1);
        int p2 = atomicAdd(&cursor[d4.z], 1);
        int p3 = atomicAdd(&cursor[d4.w], 1);
        ssrc[p0] = (unsigned short)s4.x;
        ssrc[p1] = (unsigned short)s4.y;
        ssrc[p2] = (unsigned short)s4.z;
        ssrc[p3] = (unsigned short)s4.w;
        return;
    }
    const int nt = b / RB;
    const int tM = (b - nt * RB) * 128;

    // stage B col-tile: 64 cols x 256 k via ds_write_b128 (4 chunks/thread)
#pragma unroll
    for (int it = 0; it < 4; ++it) {
        int chunk = it * 512 + tid;          // 2048 chunks of 8 k
        int col = chunk >> 5;
        int k0 = (chunk & 31) * 8;
        short8v v = *reinterpret_cast<const short8v*>(BT + (size_t)(nt * 64 + col) * 256 + k0);
        *reinterpret_cast<short8v*>(&BsT[col * 264 + k0]) = v;
    }
    __syncthreads();

    const int w  = tid >> 6;   // 0..7 row-groups
    const int l  = tid & 63;
    const int lg = l >> 4;
    const int lr = l & 15;

    int rowA = tM + w * 16 + lr;
    if (rowA > M - 1) rowA = M - 1;
    const unsigned short* Arow = A + (size_t)rowA * 256 + lg * 8;
    short8v av[8];
#pragma unroll
    for (int kt = 0; kt < 8; ++kt)
        av[kt] = *reinterpret_cast<const short8v*>(Arow + kt * 32);

    floatx4 acc[4] = {};
#pragma unroll
    for (int kt = 0; kt < 8; ++kt) {
#pragma unroll
        for (int n = 0; n < 4; ++n) {
            short8v bv = *reinterpret_cast<const short8v*>(&BsT[(n * 16 + lr) * 264 + kt * 32 + lg * 8]);
            acc[n] = __builtin_amdgcn_mfma_f32_16x16x32_bf16(av[kt], bv, acc[n], 0, 0, 0);
        }
    }

    float ps[2][4] = {}, pd[2][4] = {};
#pragma unroll
    for (int n = 0; n < 4; ++n) {
        int hd2 = n >> 1;
        float asv = att_src[(nt * 2 + hd2) * 32 + (n & 1) * 16 + lr];
        float adv = att_dst[(nt * 2 + hd2) * 32 + (n & 1) * 16 + lr];
        int col = nt * 64 + n * 16 + lr;
#pragma unroll
        for (int r = 0; r < 4; ++r) {
            int row = tM + w * 16 + lg * 4 + r;  // C/D: row=(lane>>4)*4+reg
            float v = acc[n][r];
            if (row < M) hb[(size_t)row * 256 + col] = f2bf(v);
            ps[hd2][r] += v * asv;
            pd[hd2][r] += v * adv;
        }
    }
#pragma unroll
    for (int off = 1; off < 16; off <<= 1) {
#pragma unroll
        for (int hd2 = 0; hd2 < 2; ++hd2)
#pragma unroll
            for (int r = 0; r < 4; ++r) {
                ps[hd2][r] += __shfl_xor(ps[hd2][r], off, 64);
                pd[hd2][r] += __shfl_xor(pd[hd2][r], off, 64);
            }
    }
    if (lr == 0) {
#pragma unroll
        for (int hd2 = 0; hd2 < 2; ++hd2)
#pragma unroll
            for (int r = 0; r < 4; ++r) {
                int row = tM + w * 16 + lg * 4 + r;
                if (row < M) {
                    a_src[(size_t)row * 8 + nt * 2 + hd2] = ps[hd2][r];
                    a_dst[(size_t)row * 8 + nt * 2 + hd2] = pd[hd2][r];
                }
            }
    }
}

// ------ GEMM2 (LDS-staged, 8 waves): out[M,64] = g @ W_lin + b_lin ----------
__launch_bounds__(512)
__global__ void k_gemm2(const unsigned short* __restrict__ A,
                        const unsigned short* __restrict__ BT,  // [col][k]
                        float* __restrict__ C,
                        const float* __restrict__ bias, int M) {
    __shared__ unsigned short BsT[64 * 264];
    const int tid = threadIdx.x;
    const int tM = blockIdx.x * 128;

#pragma unroll
    for (int it = 0; it < 4; ++it) {
        int chunk = it * 512 + tid;
        int col = chunk >> 5;
        int k0 = (chunk & 31) * 8;
        short8v v = *reinterpret_cast<const short8v*>(BT + (size_t)col * 256 + k0);
        *reinterpret_cast<short8v*>(&BsT[col * 264 + k0]) = v;
    }
    __syncthreads();

    const int w  = tid >> 6;
    const int l  = tid & 63;
    const int lg = l >> 4;
    const int lr = l & 15;

    int rowA = tM + w * 16 + lr;
    if (rowA > M - 1) rowA = M - 1;
    const unsigned short* Arow = A + (size_t)rowA * 256 + lg * 8;

    floatx4 acc[4] = {};
#pragma unroll
    for (int kt = 0; kt < 8; ++kt) {
        short8v av = *reinterpret_cast<const short8v*>(Arow + kt * 32);
#pragma unroll
        for (int n = 0; n < 4; ++n) {
            short8v bv = *reinterpret_cast<const short8v*>(&BsT[(n * 16 + lr) * 264 + kt * 32 + lg * 8]);
            acc[n] = __builtin_amdgcn_mfma_f32_16x16x32_bf16(av, bv, acc[n], 0, 0, 0);
        }
    }
#pragma unroll
    for (int n = 0; n < 4; ++n) {
        int col = n * 16 + lr;
        float badd = bias[col];
#pragma unroll
        for (int r = 0; r < 4; ++r) {
            int row = tM + w * 16 + lg * 4 + r;
            if (row < M) C[(size_t)row * 64 + col] = acc[n][r] + badd;
        }
    }
}

// ------ fused aggregate: softmax-weighted sum + bias + relu -> bf16 ---------
__launch_bounds__(256)
__global__ void k_agg(const int* __restrict__ row_start, const int* __restrict__ row_end,
                      const unsigned short* __restrict__ sorted_src,
                      const float* __restrict__ a_src, const float* __restrict__ a_dst,
                      const unsigned short* __restrict__ hb,
                      const float* __restrict__ bias_gat,
                      unsigned short* __restrict__ gb, int N) {
    int n = blockIdx.x * 4 + (threadIdx.x >> 6);
    if (n >= N) return;
    int lane = threadIdx.x & 63;
    int hd = lane >> 3;
    int start = row_start[n], end = row_end[n];
    float ad = a_dst[(size_t)n * 8 + hd];
    float ax = 0.f, ay = 0.f, az = 0.f, aw = 0.f, den = 0.f;
    float bx = 0.f, by = 0.f, bz = 0.f, bw = 0.f, den2 = 0.f;
    for (int j0 = start; j0 < end; j0 += 64) {
        int idx = j0 + lane;
        int sv = (idx < end) ? (int)sorted_src[idx] : 0;
        int cnt = end - j0; if (cnt > 64) cnt = 64;
        int jj = 0;
        for (; jj + 3 < cnt; jj += 4) {
            int s0 = __shfl(sv, jj);
            int s1 = __shfl(sv, jj + 1);
            int s2 = __shfl(sv, jj + 2);
            int s3 = __shfl(sv, jj + 3);
            float v0 = a_src[(size_t)s0 * 8 + hd] + ad;
            float v1 = a_src[(size_t)s1 * 8 + hd] + ad;
            float v2 = a_src[(size_t)s2 * 8 + hd] + ad;
            float v3 = a_src[(size_t)s3 * 8 + hd] + ad;
            ushort4 h0 = *reinterpret_cast<const ushort4*>(hb + (size_t)s0 * 256 + lane * 4);
            ushort4 h1 = *reinterpret_cast<const ushort4*>(hb + (size_t)s1 * 256 + lane * 4);
            ushort4 h2 = *reinterpret_cast<const ushort4*>(hb + (size_t)s2 * 256 + lane * 4);
            ushort4 h3 = *reinterpret_cast<const ushort4*>(hb + (size_t)s3 * 256 + lane * 4);
            v0 = v0 > 0.f ? v0 : 0.2f * v0;
            v1 = v1 > 0.f ? v1 : 0.2f * v1;
            v2 = v2 > 0.f ? v2 : 0.2f * v2;
            v3 = v3 > 0.f ? v3 : 0.2f * v3;
            float e0 = __expf(v0), e1 = __expf(v1), e2 = __expf(v2), e3 = __expf(v3);
            den  += e0 + e2; den2 += e1 + e3;
            ax += e0 * b2f(h0.x); ay += e0 * b2f(h0.y);
            az += e0 * b2f(h0.z); aw += e0 * b2f(h0.w);
            bx += e1 * b2f(h1.x); by += e1 * b2f(h1.y);
            bz += e1 * b2f(h1.z); bw += e1 * b2f(h1.w);
            ax += e2 * b2f(h2.x); ay += e2 * b2f(h2.y);
            az += e2 * b2f(h2.z); aw += e2 * b2f(h2.w);
            bx += e3 * b2f(h3.x); by += e3 * b2f(h3.y);
            bz += e3 * b2f(h3.z); bw += e3 * b2f(h3.w);
        }
        for (; jj < cnt; ++jj) {
            int s0 = __shfl(sv, jj);
            float v0 = a_src[(size_t)s0 * 8 + hd] + ad;
            v0 = v0 > 0.f ? v0 : 0.2f * v0;
            float e0 = __expf(v0);
            ushort4 h0 = *reinterpret_cast<const ushort4*>(hb + (size_t)s0 * 256 + lane * 4);
            den += e0;
            ax += e0 * b2f(h0.x); ay += e0 * b2f(h0.y);
            az += e0 * b2f(h0.z); aw += e0 * b2f(h0.w);
        }
    }
    float inv = 1.0f / (den + den2 + 1e-16f);
    float4 b4 = *reinterpret_cast<const float4*>(bias_gat + lane * 4);
    ushort4 o;
    o.x = f2bf(fmaxf((ax + bx) * inv + b4.x, 0.f));
    o.y = f2bf(fmaxf((ay + by) * inv + b4.y, 0.f));
    o.z = f2bf(fmaxf((az + bz) * inv + b4.z, 0.f));
    o.w = f2bf(fmaxf((aw + bw) * inv + b4.w, 0.f));
    reinterpret_cast<ushort4*>(gb)[(size_t)n * 64 + lane] = o;
}

extern "C" void kernel_launch(void* const* d_in, const int* in_sizes, int n_in,
                              void* d_out, int out_size, void* d_ws, size_t ws_size,
                              hipStream_t stream) {
    const float* x        = (const float*)d_in[0];
    const int*   ei       = (const int*)d_in[1];
    const float* W_gat    = (const float*)d_in[2];
    const float* att_src  = (const float*)d_in[3];
    const float* att_dst  = (const float*)d_in[4];
    const float* bias_gat = (const float*)d_in[5];
    const float* W_lin    = (const float*)d_in[6];
    const float* b_lin    = (const float*)d_in[7];
    float* out = (float*)d_out;

    const int N  = in_sizes[0] / 256;   // 50000
    const int E  = in_sizes[1] / 2;     // 800000
    const int EE = E + N;

    char* ws = (char*)d_ws;
    size_t off = 0;
    auto alloc = [&](size_t bytes) -> void* {
        void* p = ws + off;
        off = (off + bytes + 255) & ~(size_t)255;
        return p;
    };
    unsigned short* hb       = (unsigned short*)alloc((size_t)N * 256 * 2);
    float*          a_srcv   = (float*)alloc((size_t)N * 8 * 4);
    float*          a_dstv   = (float*)alloc((size_t)N * 8 * 4);
    int*            cnt      = (int*)alloc((size_t)N * 4);
    int*            rowst    = (int*)alloc((size_t)N * 4);
    int*            cursor   = (int*)alloc((size_t)N * 4);
    int*            bsum     = (int*)alloc(SCAN_NB * 4);
    unsigned short* ssrc     = (unsigned short*)alloc((size_t)EE * 2);
    unsigned short* xb       = (unsigned short*)alloc((size_t)N * 256 * 2);  // reused as gb
    unsigned short* wbT      = (unsigned short*)alloc(256 * 256 * 2);
    unsigned short* wlbT     = (unsigned short*)alloc(64 * 256 * 2);

    hipMemsetAsync(cnt, 0, (size_t)N * 4, stream);

    // conversions + W transposes + histogram
    k_prep<<<2048, 256, 0, stream>>>(x, xb, N * 256 / 4,
                                     W_gat, wbT, W_lin, wlbT, ei, cnt, E);

    // counting-sort scan (+ self-loop pre-placement)
    k_scan_a<<<SCAN_NB, 256, 0, stream>>>(cnt, bsum, N);
    k_scan_bc<<<SCAN_NB, 256, 0, stream>>>(cnt, bsum, rowst, cursor, ssrc, N);

    // fused GEMM1(+attn epilogue) || scatter, 512-thread blocks
    const int RB  = (N + 127) / 128;
    const int GB1 = RB * 4;
    const int SB  = (E / 4 + 511) / 512;
    k_gs<<<GB1 + SB, 512, 0, stream>>>(xb, wbT, att_src, att_dst, hb, a_srcv, a_dstv,
                                       N, RB, GB1, ei, cursor, ssrc, E);

    // fused segment softmax + aggregate + bias + relu -> bf16 (into xb as gb)
    k_agg<<<(N + 3) / 4, 256, 0, stream>>>(rowst, cursor, ssrc, a_srcv, a_dstv, hb,
                                           bias_gat, xb, N);

    // GEMM2: out = g @ W_lin + b_lin
    k_gemm2<<<(N + 127) / 128, 512, 0, stream>>>(xb, wlbT, out, b_lin, N);
}